// Round 2
// baseline (236.508 us; speedup 1.0000x reference)
//
#include <hip/hip_runtime.h>
#include <math.h>

#define T_DIM 4096
#define B_DIM 8
#define C_DIM 1024
#define H_DIM 16
#define K_DIM 31
#define PAD_L 30
#define TILE_T 32
#define WIN (TILE_T + PAD_L)   // 62
#define BLOCK 256

// One thread per (b,c) column, TILE_T consecutive t per thread.
// Lanes -> consecutive c -> fully coalesced 256B/wave accesses.
// A wave spans exactly one head (R = C/H = 64), so taps are wave-uniform
// and live in SGPRs via readfirstlane.
__global__ __launch_bounds__(BLOCK, 2) void lightconv_kernel(
    const float* __restrict__ x,
    const float* __restrict__ w,
    float* __restrict__ out)
{
    __shared__ float s_taps[4][K_DIM];   // 4 heads per 256-thread block

    const int tid    = threadIdx.x;
    const int colBlk = blockIdx.x;       // 0..31  (B*C / BLOCK)
    const int tBlk   = blockIdx.y;       // 0..127 (T / TILE_T)
    const int cc     = colBlk * BLOCK + tid;   // flat b*C + c
    const int t0     = tBlk * TILE_T;

    // ---- per-block softmax of the block's 4 heads (threads 0..3) ----
    if (tid < 4) {
        const int c0 = (colBlk * BLOCK) % C_DIM;   // multiple of 256
        const int h  = (c0 >> 6) + tid;            // head index
        const float* wr = w + h * K_DIM;
        float m = -1e30f;
        #pragma unroll
        for (int k = 0; k < K_DIM; ++k) m = fmaxf(m, wr[k]);
        float s = 0.0f;
        #pragma unroll
        for (int k = 0; k < K_DIM; ++k) {
            float e = __expf(wr[k] - m);
            s_taps[tid][k] = e;
            s += e;
        }
        const float inv = 1.0f / s;
        #pragma unroll
        for (int k = 0; k < K_DIM; ++k) s_taps[tid][k] *= inv;
    }
    __syncthreads();

    // ---- taps -> SGPRs (wave-uniform: one head per wave) ----
    const int hl = tid >> 6;
    float taps[K_DIM];
    #pragma unroll
    for (int k = 0; k < K_DIM; ++k) {
        // each lane reads the same LDS address -> uniform value
        taps[k] = __int_as_float(
            __builtin_amdgcn_readfirstlane(__float_as_int(s_taps[hl][k])));
    }

    const long stride = (long)B_DIM * C_DIM;   // 8192 elems between t's

    // ---- batched load of the full window [t0-30, t0+31] ----
    float xv[WIN];
    const float* px = x + (long)(t0 - PAD_L) * stride + cc;
    if (t0 >= PAD_L) {                         // wave-uniform: all tBlk >= 1
        #pragma unroll
        for (int j = 0; j < WIN; ++j) xv[j] = px[(long)j * stride];
    } else {                                   // only tBlk == 0 pays the guard
        #pragma unroll
        for (int j = 0; j < WIN; ++j)
            xv[j] = (j >= PAD_L) ? px[(long)j * stride] : 0.0f;
    }

    // ---- 32 outputs, 4-way split accumulation (chain length 8) ----
    float* po = out + (long)t0 * stride + cc;
    #pragma unroll
    for (int i = 0; i < TILE_T; ++i) {
        float a0 = 0.0f, a1 = 0.0f, a2 = 0.0f, a3 = 0.0f;
        #pragma unroll
        for (int k = 0; k < 8; ++k)  a0 = fmaf(taps[k],      xv[i + k],      a0);
        #pragma unroll
        for (int k = 0; k < 8; ++k)  a1 = fmaf(taps[8 + k],  xv[i + 8 + k],  a1);
        #pragma unroll
        for (int k = 0; k < 8; ++k)  a2 = fmaf(taps[16 + k], xv[i + 16 + k], a2);
        #pragma unroll
        for (int k = 0; k < 7; ++k)  a3 = fmaf(taps[24 + k], xv[i + 24 + k], a3);
        po[(long)i * stride] = (a0 + a1) + (a2 + a3);
    }
}

extern "C" void kernel_launch(void* const* d_in, const int* in_sizes, int n_in,
                              void* d_out, int out_size, void* d_ws, size_t ws_size,
                              hipStream_t stream) {
    const float* x = (const float*)d_in[0];    // [T, B, C] fp32
    const float* w = (const float*)d_in[1];    // [H, K]    fp32
    float* out = (float*)d_out;                // [T, B, C] fp32

    dim3 grid((B_DIM * C_DIM) / BLOCK, T_DIM / TILE_T);  // (32, 128)
    lightconv_kernel<<<grid, BLOCK, 0, stream>>>(x, w, out);
}

// Round 3
// 233.450 us; speedup vs baseline: 1.0131x; 1.0131x over previous
//
#include <hip/hip_runtime.h>
#include <math.h>

#define T_DIM 4096
#define B_DIM 8
#define C_DIM 1024
#define H_DIM 16
#define K_DIM 31
#define PAD_L 30
#define TILE_T 32
#define WIN (TILE_T + PAD_L)   // 62
#define BLOCK 256

// One thread per (b,c) column, TILE_T consecutive t per thread.
// Lanes -> consecutive c -> fully coalesced 256B/wave accesses.
// A wave spans exactly one head (R = C/H = 64): taps are wave-uniform SGPRs.
//
// Key structural fix vs R2: sched_barrier(0) between the unrolled load phase
// and the compute phase forces all 62 window loads to issue back-to-back
// (62 outstanding vmem ops/wave) instead of the compiler's just-in-time
// load sinking that serialized each wave on memory latency (VGPR=52 tell).
__global__ __launch_bounds__(BLOCK, 2) void lightconv_kernel(
    const float* __restrict__ x,
    const float* __restrict__ w,
    float* __restrict__ out)
{
    __shared__ float s_taps[4][K_DIM];   // 4 heads per 256-thread block

    const int tid    = threadIdx.x;
    const int colBlk = blockIdx.x;       // 0..31  (B*C / BLOCK)
    const int tBlk   = blockIdx.y;       // 0..127 (T / TILE_T)
    const int cc     = colBlk * BLOCK + tid;   // flat b*C + c
    const int t0     = tBlk * TILE_T;

    // ---- per-block softmax of the block's 4 heads (threads 0..3) ----
    if (tid < 4) {
        const int c0 = (colBlk * BLOCK) % C_DIM;   // multiple of 256
        const int h  = (c0 >> 6) + tid;            // head index
        const float* wr = w + h * K_DIM;
        float m = -1e30f;
        #pragma unroll
        for (int k = 0; k < K_DIM; ++k) m = fmaxf(m, wr[k]);
        float s = 0.0f;
        #pragma unroll
        for (int k = 0; k < K_DIM; ++k) {
            float e = __expf(wr[k] - m);
            s_taps[tid][k] = e;
            s += e;
        }
        const float inv = 1.0f / s;
        #pragma unroll
        for (int k = 0; k < K_DIM; ++k) s_taps[tid][k] *= inv;
    }
    __syncthreads();

    // ---- taps -> SGPRs (wave-uniform: one head per wave) ----
    const int hl = tid >> 6;
    float taps[K_DIM];
    #pragma unroll
    for (int k = 0; k < K_DIM; ++k) {
        taps[k] = __int_as_float(
            __builtin_amdgcn_readfirstlane(__float_as_int(s_taps[hl][k])));
    }

    const long stride = (long)B_DIM * C_DIM;   // 8192 elems between t's

    // ---- batched load of the full window [t0-30, t0+31] ----
    float xv[WIN];
    const float* px = x + (long)(t0 - PAD_L) * stride + cc;
    if (t0 >= PAD_L) {                         // wave-uniform: all tBlk >= 1
        #pragma unroll
        for (int j = 0; j < WIN; ++j) xv[j] = px[(long)j * stride];
    } else {                                   // only tBlk == 0 pays the guard
        #pragma unroll
        for (int j = 0; j < WIN; ++j)
            xv[j] = (j >= PAD_L) ? px[(long)j * stride] : 0.0f;
    }

    // No instruction may cross: all 62 loads issue before the first FMA.
    __builtin_amdgcn_sched_barrier(0);

    // ---- 32 outputs, 4-way split accumulation (chain length 8) ----
    float* po = out + (long)t0 * stride + cc;
    #pragma unroll
    for (int i = 0; i < TILE_T; ++i) {
        float a0 = 0.0f, a1 = 0.0f, a2 = 0.0f, a3 = 0.0f;
        #pragma unroll
        for (int k = 0; k < 8; ++k)  a0 = fmaf(taps[k],      xv[i + k],      a0);
        #pragma unroll
        for (int k = 0; k < 8; ++k)  a1 = fmaf(taps[8 + k],  xv[i + 8 + k],  a1);
        #pragma unroll
        for (int k = 0; k < 8; ++k)  a2 = fmaf(taps[16 + k], xv[i + 16 + k], a2);
        #pragma unroll
        for (int k = 0; k < 7; ++k)  a3 = fmaf(taps[24 + k], xv[i + 24 + k], a3);
        // nontemporal: out is never re-read; don't let it evict x from L3
        __builtin_nontemporal_store((a0 + a1) + (a2 + a3), po + (long)i * stride);
    }
}

extern "C" void kernel_launch(void* const* d_in, const int* in_sizes, int n_in,
                              void* d_out, int out_size, void* d_ws, size_t ws_size,
                              hipStream_t stream) {
    const float* x = (const float*)d_in[0];    // [T, B, C] fp32
    const float* w = (const float*)d_in[1];    // [H, K]    fp32
    float* out = (float*)d_out;                // [T, B, C] fp32

    dim3 grid((B_DIM * C_DIM) / BLOCK, T_DIM / TILE_T);  // (32, 128)
    lightconv_kernel<<<grid, BLOCK, 0, stream>>>(x, w, out);
}